// Round 7
// baseline (84.564 us; speedup 1.0000x reference)
//
#include <hip/hip_runtime.h>

#define DEVINL __device__ __forceinline__

typedef float f32x2 __attribute__((ext_vector_type(2)));

// ---------------------------------------------------------------------------
// Compile-time circuit constants via GF(2) linear-map tracking.
// Physical index q (10 bits): bits 9..5 = lane l5 (5 bits), bits 4..0 = reg.
// Lane bit 5 of the hw lane = SAMPLE SELECT (2 samples per wave).
//
// Round-7: BASIS CHANGE.  Logical position space p relates to physical q by
// p = P q with P = blockdiag(A on lane bits, I on reg bits) -- block
// structure preserves the tensor-product state construction.  The 10 layer-1
// gate masks are linearly independent, and their 6 lane-parts contain one
// DOUBLED vector, so A^{-1} can map them to chosen targets:
//   u1->16 (one ds_swizzle gate), u2->8 (DPP row_ror:8), u3->7 (DPP
//   row_half_mirror), u4->2 (DPP quad), u5->1 (DPP quad, used by TWO gates).
// Gate inventory becomes 4 reg-local + 5 DPP + 1 swizzle (was 4 swizzle +
// 2 DPP): gate LDS 256 -> 64 ops/wave.  All transformed masks/rows/selectors
// are computed constexpr in build_circ (A = U^{-1} by Gaussian elimination,
// rows via A^T) and the final inventory is static_asserted.
// Reg-side tables/WHT/phase-folding identical to R6; lane-side construction
// uses popc-parity selectors instead of bit-selects.
// ---------------------------------------------------------------------------
struct GC { int laneXor, regXor, rowL, rowR; };
struct Circ { GC g[20]; int sgnL[10], sgnR[10]; int lsel[5]; };

constexpr Circ build_circ() {
    Circ c{};
    unsigned A[10] = {};
    for (int i = 0; i < 10; ++i) A[i] = 1u << i;
    for (int w = 0; w < 10; ++w) {
        int pos = 9 - w;
        unsigned m = 1u << pos;
        c.g[w] = GC{ int(m >> 5), int(m & 31u), int(m >> 5), int(m & 31u) };
    }
    // layer 0 CNOT ring, range r=1
    for (int q = 0; q < 10; ++q) { int pc = 9 - q, pt = 9 - ((q + 1) % 10); A[pt] ^= A[pc]; }
    // invert A over GF(2)
    unsigned M[10] = {}, Inv[10] = {};
    for (int i = 0; i < 10; ++i) { M[i] = A[i]; Inv[i] = 1u << i; }
    for (int col = 0; col < 10; ++col) {
        int piv = col;
        while (!((M[piv] >> col) & 1u)) ++piv;
        unsigned tm = M[col]; M[col] = M[piv]; M[piv] = tm;
        unsigned ti = Inv[col]; Inv[col] = Inv[piv]; Inv[piv] = ti;
        for (int r = 0; r < 10; ++r)
            if (r != col && ((M[r] >> col) & 1u)) { M[r] ^= M[col]; Inv[r] ^= Inv[col]; }
    }
    // layer 1 Rot gates in p-space (5/5 split): m = A^{-1} e_pos, row = A[pos]
    for (int w = 0; w < 10; ++w) {
        int pos = 9 - w;
        unsigned m = 0;
        for (int i = 0; i < 10; ++i) m |= ((Inv[i] >> pos) & 1u) << i;
        unsigned row = A[pos];
        c.g[10 + w] = GC{ int(m >> 5), int(m & 31u), int(row >> 5), int(row & 31u) };
    }
    // layer 1 CNOT ring, range r=2
    for (int q = 0; q < 10; ++q) { int pc = 9 - q, pt = 9 - ((q + 2) % 10); A[pt] ^= A[pc]; }
    for (int q = 0; q < 10; ++q) { unsigned row = A[9 - q]; c.sgnL[q] = int(row >> 5); c.sgnR[q] = int(row & 31u); }

    // ---- basis change on the 5 lane bits -------------------------------
    // Lane-parts of the lane-involved gate masks form the chain
    // u1={b0}, u2={b0,b1}, u3={b1,b2}, u4={b2,b3}, u5={b3,b4} (u5 doubled).
    // Choose U = A_lane^{-1} mapping u1..u5 -> {16, 8, 7, 2, 1}.
    unsigned Ucols[5] = {};
    {
        unsigned tgt[5] = {16, 8, 7, 2, 1};
        unsigned acc = 0;
        // u_k = e_{k-2}+e_{k-1} chain => U e_{k-1} = xor of tgt[0..k-1]
        for (int k = 0; k < 5; ++k) { acc ^= tgt[k]; Ucols[k] = acc; }
    }
    // rows of U
    unsigned Urows[5] = {};
    for (int r = 0; r < 5; ++r)
        for (int cc = 0; cc < 5; ++cc)
            Urows[r] |= ((Ucols[cc] >> r) & 1u) << cc;
    // invert U (rows) -> Arows = rows of A_lane = U^{-1}
    unsigned MM[5] = {}, AI[5] = {};
    for (int i = 0; i < 5; ++i) { MM[i] = Urows[i]; AI[i] = 1u << i; }
    for (int col = 0; col < 5; ++col) {
        int piv = col;
        while (!((MM[piv] >> col) & 1u)) ++piv;
        unsigned tm = MM[col]; MM[col] = MM[piv]; MM[piv] = tm;
        unsigned ti = AI[col]; AI[col] = AI[piv]; AI[piv] = ti;
        for (int r = 0; r < 5; ++r)
            if (r != col && ((MM[r] >> col) & 1u)) { MM[r] ^= MM[col]; AI[r] ^= AI[col]; }
    }
    // transform gate lane masks (mu_L = U mL), lane rows (row' = A^T row =
    // xor of A-rows selected by row bits), and output sign lane masks
    for (int w = 0; w < 10; ++w) {
        unsigned mL = unsigned(c.g[10 + w].laneXor);
        unsigned nm = 0;
        for (int i = 0; i < 5; ++i) if ((mL >> i) & 1u) nm ^= Ucols[i];
        c.g[10 + w].laneXor = int(nm);
        unsigned rL = unsigned(c.g[10 + w].rowL);
        unsigned nr = 0;
        for (int i = 0; i < 5; ++i) if ((rL >> i) & 1u) nr ^= AI[i];
        c.g[10 + w].rowL = int(nr);
    }
    for (int q = 0; q < 10; ++q) {
        unsigned sL = unsigned(c.sgnL[q]);
        unsigned ns = 0;
        for (int i = 0; i < 5; ++i) if ((sL >> i) & 1u) ns ^= AI[i];
        c.sgnL[q] = int(ns);
    }
    // lane-wire selectors: wire w (0..4) sits at position 9-w = 5+o, o=4-w;
    // its selector over l5 is row o of A_lane.
    for (int o = 0; o < 5; ++o) c.lsel[o] = int(AI[o]);
    return c;
}

constexpr Circ CC = build_circ();

// Final gate inventory this schedule depends on (computed, then asserted).
static_assert(CC.g[10].laneXor == 1  && CC.g[10].regXor == 0,  "w0");
static_assert(CC.g[11].laneXor == 2  && CC.g[11].regXor == 0,  "w1");
static_assert(CC.g[12].laneXor == 7  && CC.g[12].regXor == 0,  "w2");
static_assert(CC.g[13].laneXor == 8  && CC.g[13].regXor == 0,  "w3");
static_assert(CC.g[14].laneXor == 16 && CC.g[14].regXor == 16, "w4");
static_assert(CC.g[15].laneXor == 0  && CC.g[15].regXor == 24, "w5");
static_assert(CC.g[16].laneXor == 0  && CC.g[16].regXor == 12, "w6");
static_assert(CC.g[17].laneXor == 0  && CC.g[17].regXor == 6,  "w7");
static_assert(CC.g[18].laneXor == 0  && CC.g[18].regXor == 3,  "w8");
static_assert(CC.g[19].laneXor == 1  && CC.g[19].regXor == 1,  "w9");
// Phase-folding relies on these reg rows (unchanged by the basis change).
static_assert(CC.g[10].rowR == 31, "w0 rowR");
static_assert(CC.g[11].rowR == 0,  "w1 rowR");
static_assert(CC.g[12].rowR == 0,  "w2 rowR");
static_assert(CC.g[13].rowR == 0,  "w3 rowR");
static_assert(CC.g[14].rowR == 0,  "w4 rowR");
static_assert(CC.g[15].rowR == 16, "w5 rowR");
static_assert(CC.g[16].rowR == 24, "w6 rowR");
static_assert(CC.g[17].rowR == 28, "w7 rowR");
static_assert(CC.g[18].rowR == 30, "w8 rowR");
static_assert(CC.g[19].rowR == 31, "w9 rowR");

// sign-word xor: sw has the sign in bit 31 (or is 0)
DEVINL float csw(float v, int sw) {
    return __int_as_float(__float_as_int(v) ^ sw);
}

// lane-xor fetch:
//   1,2,3 -> DPP quad_perm;  7 -> DPP row_half_mirror (0x141);
//   8 -> DPP row_ror:8 (0x128, rotation by 8 within a 16-row == xor8);
//   else (<32) -> ds_swizzle.  All patterns stay within 32-lane halves.
template<int XOR>
DEVINL float fetch(float v, int lane) {
    if constexpr (XOR == 0)      return v;
    else if constexpr (XOR == 1) return __int_as_float(__builtin_amdgcn_update_dpp(0, __float_as_int(v), 0xB1, 0xF, 0xF, true));
    else if constexpr (XOR == 2) return __int_as_float(__builtin_amdgcn_update_dpp(0, __float_as_int(v), 0x4E, 0xF, 0xF, true));
    else if constexpr (XOR == 3) return __int_as_float(__builtin_amdgcn_update_dpp(0, __float_as_int(v), 0x1B, 0xF, 0xF, true));
    else if constexpr (XOR == 7) return __int_as_float(__builtin_amdgcn_update_dpp(0, __float_as_int(v), 0x141, 0xF, 0xF, true));
    else if constexpr (XOR == 8) return __int_as_float(__builtin_amdgcn_update_dpp(0, __float_as_int(v), 0x128, 0xF, 0xF, true));
    else                         return __int_as_float(__builtin_amdgcn_ds_swizzle(__float_as_int(v), 0x1F | (XOR << 10)));
}

// forced packed FMA: a = t*b + a
DEVINL void pk_fma_acc(f32x2& a, f32x2 t, f32x2 b) {
    asm("v_pk_fma_f32 %0, %1, %2, %0" : "+v"(a) : "v"(t), "v"(b));
}

DEVINL f32x2 cmul(f32x2 a, f32x2 b) {
    f32x2 r;
    r.x = a.x * b.x - a.y * b.y;
    r.y = a.x * b.y + a.y * b.x;
    return r;
}

// ---------------------------------------------------------------------------
// Constants, computed once by qprep (wire-indexed; basis-agnostic):
// [0..39]  layer-0 Rot mats (u00r,u00i,u01r,u01i per wire)
// [40..49] layer-1 tan(th/2) per wire
// [50..69] layer-1 (cos(phi/2), -sin(phi/2)) per wire
// [70]     prod_w cos(th_w/2)
// ---------------------------------------------------------------------------
__device__ __attribute__((aligned(16))) float g_cst[80];

__global__ void qprep(const float* __restrict__ qw) {
    int g = threadIdx.x;
    if (g < 10) {
        float phi = qw[g * 3 + 0], th = qw[g * 3 + 1], om = qw[g * 3 + 2];
        float c = cosf(0.5f * th), s = sinf(0.5f * th);
        float apo = 0.5f * (phi + om), amo = 0.5f * (phi - om);
        g_cst[g * 4 + 0] =  cosf(apo) * c;
        g_cst[g * 4 + 1] = -sinf(apo) * c;
        g_cst[g * 4 + 2] = -cosf(amo) * s;
        g_cst[g * 4 + 3] = -sinf(amo) * s;
    } else if (g < 20) {
        int w = g - 10;
        float phi = qw[g * 3 + 0], th = qw[g * 3 + 1];
        float c = cosf(0.5f * th), s = sinf(0.5f * th);
        g_cst[40 + w] = s / c;
        g_cst[50 + w * 2 + 0] =  cosf(0.5f * phi);
        g_cst[50 + w * 2 + 1] = -sinf(0.5f * phi);
    } else if (g == 20) {
        float p = 1.f;
        for (int w = 0; w < 10; ++w) p *= cosf(0.5f * qw[(10 + w) * 3 + 1]);
        g_cst[70] = p;
    }
}

// per-wire embedding factor: |0> --RY(x)--> --Rot(layer0)--> (f0, f1)
DEVINL void wf(const float* cst, float xw, int w, f32x2& f0, f32x2& f1) {
    float h = 0.5f * xw;
    float s = __sinf(h), c = __cosf(h);
    float m0 = cst[w * 4 + 0], m1 = cst[w * 4 + 1], m2 = cst[w * 4 + 2], m3 = cst[w * 4 + 3];
    f0.x =  m0 * c + m2 * s;
    f0.y =  m1 * c + m3 * s;
    f1.x = -m2 * c + m0 * s;
    f1.y =  m3 * c - m1 * s;
}

// Layer-1 RY gate as fast-Givens on packed {re,im}: a' = a +- t*b.
// Lane-xor gates: two chunks {0..7,16..23} / {8..15,24..31}, each closed
// under ^regXor (regXor in {0,1,16}) -> stage-then-fma is read-before-write.
// Local gates: pairwise update with one temp.
template<int W>
DEVINL void apply_gate(f32x2 (&a2)[32], const float* cst, int lane, const int (&sw)[10]) {
    constexpr GC gc = CC.g[10 + W];
    float tt = csw(cst[40 + W], sw[W]);
    f32x2 tp; tp.x = tt;  tp.y = tt;
    f32x2 tn; tn.x = -tt; tn.y = -tt;
    if constexpr (gc.laneXor == 0) {
        #pragma unroll
        for (int r = 0; r < 32; ++r) {
            const int r2 = r ^ gc.regXor;
            if (r < r2) {
                f32x2 old = a2[r];
                const bool sR  = __builtin_popcount(unsigned(gc.rowR & r )) & 1;
                const bool sR2 = __builtin_popcount(unsigned(gc.rowR & r2)) & 1;
                pk_fma_acc(a2[r],  sR  ? tp : tn, a2[r2]);
                pk_fma_acc(a2[r2], sR2 ? tp : tn, old);
            }
        }
    } else {
        #pragma unroll
        for (int c = 0; c < 2; ++c) {
            f32x2 b2[16];
            #pragma unroll
            for (int i = 0; i < 16; ++i) {
                const int r = (i & 7) + c * 8 + ((i >> 3) << 4);
                f32x2 s = a2[r ^ gc.regXor];
                b2[i].x = fetch<gc.laneXor>(s.x, lane);
                b2[i].y = fetch<gc.laneXor>(s.y, lane);
            }
            #pragma unroll
            for (int i = 0; i < 16; ++i) {
                const int r = (i & 7) + c * 8 + ((i >> 3) << 4);
                const bool sR = __builtin_popcount(unsigned(gc.rowR & r)) & 1;
                pk_fma_acc(a2[r], sR ? tp : tn, b2[i]);
            }
        }
    }
}

__global__ __launch_bounds__(256) void qsim(const float* __restrict__ x,
                                            float* __restrict__ out, int B) {
    const float* cst = g_cst;
    int lane = threadIdx.x & 63;
    int l5 = lane & 31;                        // 5-bit lane within the sample
    int b = blockIdx.x * 8 + (threadIdx.x >> 5);   // 2 samples/wave, 8/block
    if (b >= B) return;
    const float* xb = x + b * 10;

    // ---- lane-parity sign words for the layer-1 rows (bit 31 = sign),
    //      rows already transformed to q-space (A^T) at compile time
    int sw_[10];
    #pragma unroll
    for (int w = 0; w < 10; ++w)
        sw_[w] = (__popc(unsigned(l5 & CC.g[10 + w].rowL)) & 1) << 31;

    // ---- reg-wire tables: bit0=w9, bit1=w8, bit2=w7, bit3=w6, bit4=w5
    f32x2 t01[4], t23[4], f5t[2];
    {
        f32x2 a0, a1, b0, b1;
        wf(cst, xb[9], 9, a0, a1);
        wf(cst, xb[8], 8, b0, b1);
        t01[0] = cmul(a0, b0); t01[1] = cmul(a1, b0);
        t01[2] = cmul(a0, b1); t01[3] = cmul(a1, b1);
        wf(cst, xb[7], 7, a0, a1);
        wf(cst, xb[6], 6, b0, b1);
        t23[0] = cmul(a0, b0); t23[1] = cmul(a1, b0);
        t23[2] = cmul(a0, b1); t23[3] = cmul(a1, b1);
        wf(cst, xb[5], 5, f5t[0], f5t[1]);
    }

    // ---- lane-signed RZ(phi) phase constants E_w = (cos, -+sin)
    f32x2 E0; E0.x = cst[50];      E0.y = csw(cst[51], sw_[0]);
    f32x2 E1; E1.x = cst[52];      E1.y = csw(cst[53], sw_[1]);
    f32x2 E2; E2.x = cst[54];      E2.y = csw(cst[55], sw_[2]);
    f32x2 E3; E3.x = cst[56];      E3.y = csw(cst[57], sw_[3]);
    f32x2 E4; E4.x = cst[58];      E4.y = csw(cst[59], sw_[4]);
    f32x2 E5; E5.x = cst[60];      E5.y = csw(cst[61], sw_[5]);
    f32x2 E6; E6.x = cst[62];      E6.y = csw(cst[63], sw_[6]);
    f32x2 E7; E7.x = cst[64];      E7.y = csw(cst[65], sw_[7]);
    f32x2 E8; E8.x = cst[66];      E8.y = csw(cst[67], sw_[8]);
    f32x2 E9; E9.x = cst[68];      E9.y = csw(cst[69], sw_[9]);

    // ---- lane factor: E_A (w1..w4) * cos-product * lane-wire factors
    //      (wire selectors are parities of l5 against rows of A_lane)
    f32x2 lf;
    {
        f32x2 ea = cmul(cmul(E1, E2), cmul(E3, E4));
        float sc = cst[70];
        lf.x = ea.x * sc; lf.y = ea.y * sc;
        #pragma unroll
        for (int jj = 0; jj < 5; ++jj) {
            int w = 4 - jj;                    // wire w <-> selector lsel[jj]
            f32x2 f0, f1;
            wf(cst, xb[w], w, f0, f1);
            int bit = __popc(unsigned(l5 & CC.lsel[jj])) & 1;
            f32x2 p; p.x = bit ? f1.x : f0.x; p.y = bit ? f1.y : f0.y;
            lf = cmul(lf, p);
        }
    }

    // ---- fold w5 phase into f5 (bit4); build V/H phase products
    f32x2 f5p[2];
    f5p[0] = cmul(f5t[0], E5);
    { f32x2 e5c; e5c.x = E5.x; e5c.y = -E5.y; f5p[1] = cmul(f5t[1], e5c); }
    f32x2 V00 = cmul(E6, E7);
    f32x2 V01; { f32x2 e7c; e7c.x = E7.x; e7c.y = -E7.y; V01 = cmul(E6, e7c); }
    f32x2 EB = cmul(E9, E0);
    f32x2 H0 = cmul(E8, EB);
    f32x2 H1; { f32x2 ebc; ebc.x = EB.x; ebc.y = -EB.y; H1 = cmul(E8, ebc); }

    // ---- tf[8] = t23[j&3] * f5p[j>>2] * V^{s6,s7}   (j = bits 4,3,2 of r)
    f32x2 tf[8];
    #pragma unroll
    for (int j = 0; j < 8; ++j) {
        f32x2 tA = cmul(t23[j & 3], f5p[j >> 2]);
        const int s6 = ((j >> 2) ^ (j >> 1)) & 1;
        const int s7 = s6 ^ (j & 1);
        f32x2 V;
        V.x = s6 ? (s7 ? V00.x : V01.x) : (s7 ? V01.x : V00.x);
        V.y = s6 ? -(s7 ? V00.y : V01.y) : (s7 ? V01.y : V00.y);
        tf[j] = cmul(tA, V);
    }

    // ---- g4 = lf * t01 ; amps = (g4 (x) tf) * G(r)
    f32x2 g4[4];
    #pragma unroll
    for (int v = 0; v < 4; ++v) g4[v] = cmul(lf, t01[v]);
    f32x2 a2[32];
    #pragma unroll
    for (int r = 0; r < 32; ++r) {
        f32x2 t = cmul(g4[r & 3], tf[(r >> 2) & 7]);
        f32x2 G;
        G.x = (r & 1) ? H1.x : H0.x;
        G.y = (r & 1) ? H1.y : H0.y;
        if (__builtin_popcount(unsigned(r & 30)) & 1) G.y = -G.y;  // conj
        a2[r] = cmul(t, G);
    }

    // ---- layer-1 RY gates (commuting).  The single swizzle gate (w4) goes
    //      first so its LDS latency hides under the DPP/local gates.
    apply_gate<4>(a2, cst, lane, sw_);   // swz16 (reg^16)
    apply_gate<5>(a2, cst, lane, sw_);   // local reg^24
    apply_gate<0>(a2, cst, lane, sw_);   // DPP xor1
    apply_gate<6>(a2, cst, lane, sw_);   // local reg^12
    apply_gate<1>(a2, cst, lane, sw_);   // DPP xor2
    apply_gate<7>(a2, cst, lane, sw_);   // local reg^6
    apply_gate<2>(a2, cst, lane, sw_);   // DPP xor7 (row_half_mirror)
    apply_gate<8>(a2, cst, lane, sw_);   // local reg^3
    apply_gate<3>(a2, cst, lane, sw_);   // DPP xor8 (row_ror:8)
    apply_gate<9>(a2, cst, lane, sw_);   // DPP xor1 (reg^1)

    // ---- probabilities + reg-WHT stages 1,2,4,8 (stage 16 pruned into e[q])
    float wv[32];
    #pragma unroll
    for (int r = 0; r < 32; ++r) wv[r] = a2[r].x * a2[r].x + a2[r].y * a2[r].y;
    #pragma unroll
    for (int bS = 1; bS < 16; bS <<= 1) {
        #pragma unroll
        for (int r = 0; r < 32; ++r) {
            if (!(r & bS)) {
                float xv = wv[r], yv = wv[r | bS];
                wv[r]      = xv + yv;
                wv[r | bS] = xv - yv;
            }
        }
    }

    float e[10];
    #pragma unroll
    for (int q = 0; q < 10; ++q) {
        const int R = CC.sgnR[q];
        float num = (R & 16) ? (wv[R ^ 16] - wv[R]) : (wv[R] + wv[R ^ 16]);
        int slq = __popc(unsigned(l5 & CC.sgnL[q])) & 1;
        e[q] = csw(num, slq << 31);
    }

    // ---- lane reduction within each 32-half: DPP quad-reduce, slot-pack to
    //      3, then xor4 (swz) / xor8 (DPP ror8) / xor16 (swz)
    #pragma unroll
    for (int q = 0; q < 10; ++q) {
        e[q] += fetch<1>(e[q], lane);
        e[q] += fetch<2>(e[q], lane);
    }
    int s = l5 & 3;
    bool s1 = (s & 1) != 0, s2 = (s & 2) != 0;
    float v0 = s1 ? e[1] : e[0];
    float u0 = s1 ? e[3] : e[2];
    v0 = s2 ? u0 : v0;
    float v1 = s1 ? e[5] : e[4];
    float u1 = s1 ? e[7] : e[6];
    v1 = s2 ? u1 : v1;
    float v2 = s1 ? e[9] : e[8];

    v0 += fetch<4>(v0, lane);   v1 += fetch<4>(v1, lane);   v2 += fetch<4>(v2, lane);
    v0 += fetch<8>(v0, lane);   v1 += fetch<8>(v1, lane);   v2 += fetch<8>(v2, lane);
    v0 += fetch<16>(v0, lane);  v1 += fetch<16>(v1, lane);  v2 += fetch<16>(v2, lane);

    // lane l5==q holds full sum of e[q] in v_{q>>2} (slot matches l5&3)
    float vo = v0;
    int hi = l5 >> 2;
    vo = (hi == 1) ? v1 : vo;
    vo = (hi == 2) ? v2 : vo;
    if (l5 < 10) out[b * 10 + l5] = vo;
}

extern "C" void kernel_launch(void* const* d_in, const int* in_sizes, int n_in,
                              void* d_out, int out_size, void* d_ws, size_t ws_size,
                              hipStream_t stream) {
    const float* x  = (const float*)d_in[0];
    const float* qw = (const float*)d_in[1];
    float* out = (float*)d_out;
    int B = in_sizes[0] / 10;
    int blocks = (B + 7) / 8;   // 8 samples per 256-thread block (2 per wave)
    hipLaunchKernelGGL(qprep, dim3(1), dim3(64), 0, stream, qw);
    hipLaunchKernelGGL(qsim, dim3(blocks), dim3(256), 0, stream, x, out, B);
}

// Round 8
// 83.056 us; speedup vs baseline: 1.0181x; 1.0181x over previous
//
#include <hip/hip_runtime.h>

#define DEVINL __device__ __forceinline__

typedef float f32x2 __attribute__((ext_vector_type(2)));

// ---------------------------------------------------------------------------
// Compile-time circuit constants via GF(2) linear-map tracking.
// Physical index q (10 bits): bits 9..5 = lane l5 (5 bits), bits 4..0 = reg.
// Lane bit 5 of the hw lane = SAMPLE SELECT (2 samples per wave).
//
// Round-8 (R7 post-mortem: DPP-maximal basis regressed ~2.5us -- 192 mov_dpp
// landed on the critical VALU pipe while LDS sat idle; R3's lesson again):
//  * Basis retargeted to 2 swizzle + 4 DPP: w4->16(swz,reg^16), w3->8(DPP
//    row_ror:8), w2->2(DPP quad), w1->12(swz), w0/w9->1(DPP quad).  xor7/
//    xor8 DPP patterns were correctness-proven by R7's pass.  128 mov_dpp
//    move back to the idle LDS pipe (~134 LDS ops/wave, still hidden).
//  * H folded into g4: G(r)'s H-index is determined by r&3, so g4H[4][2]
//    (8 cmul) replaces the per-amp G multiply: 68 -> 44 cmul (-96 inst).
//  * No staging arrays: regXor==0 lane gates do fetch-then-fma per register
//    (lockstep-safe); paired gates (reg^16, reg^1) use 2 temps per pair.
//    Peak VGPR drops ~30 -> better occupancy.
//  * x loads vectorized (5x dwordx2, 8B-aligned); lane-factor chain tree'd.
// ---------------------------------------------------------------------------
struct GC { int laneXor, regXor, rowL, rowR; };
struct Circ { GC g[20]; int sgnL[10], sgnR[10]; int lsel[5]; };

constexpr Circ build_circ() {
    Circ c{};
    unsigned A[10] = {};
    for (int i = 0; i < 10; ++i) A[i] = 1u << i;
    for (int w = 0; w < 10; ++w) {
        int pos = 9 - w;
        unsigned m = 1u << pos;
        c.g[w] = GC{ int(m >> 5), int(m & 31u), int(m >> 5), int(m & 31u) };
    }
    // layer 0 CNOT ring, range r=1
    for (int q = 0; q < 10; ++q) { int pc = 9 - q, pt = 9 - ((q + 1) % 10); A[pt] ^= A[pc]; }
    // invert A over GF(2)
    unsigned M[10] = {}, Inv[10] = {};
    for (int i = 0; i < 10; ++i) { M[i] = A[i]; Inv[i] = 1u << i; }
    for (int col = 0; col < 10; ++col) {
        int piv = col;
        while (!((M[piv] >> col) & 1u)) ++piv;
        unsigned tm = M[col]; M[col] = M[piv]; M[piv] = tm;
        unsigned ti = Inv[col]; Inv[col] = Inv[piv]; Inv[piv] = ti;
        for (int r = 0; r < 10; ++r)
            if (r != col && ((M[r] >> col) & 1u)) { M[r] ^= M[col]; Inv[r] ^= Inv[col]; }
    }
    // layer 1 Rot gates in p-space (5/5 split): m = A^{-1} e_pos, row = A[pos]
    for (int w = 0; w < 10; ++w) {
        int pos = 9 - w;
        unsigned m = 0;
        for (int i = 0; i < 10; ++i) m |= ((Inv[i] >> pos) & 1u) << i;
        unsigned row = A[pos];
        c.g[10 + w] = GC{ int(m >> 5), int(m & 31u), int(row >> 5), int(row & 31u) };
    }
    // layer 1 CNOT ring, range r=2
    for (int q = 0; q < 10; ++q) { int pc = 9 - q, pt = 9 - ((q + 2) % 10); A[pt] ^= A[pc]; }
    for (int q = 0; q < 10; ++q) { unsigned row = A[9 - q]; c.sgnL[q] = int(row >> 5); c.sgnR[q] = int(row & 31u); }

    // ---- basis change on the 5 lane bits -------------------------------
    // Lane-parts of the lane-involved gate masks form the chain
    // u1={b0}(w4), u2={b0,b1}(w3), u3={b1,b2}(w2), u4={b2,b3}(w1),
    // u5={b3,b4}(w0 AND w9, doubled).  Map u1..u5 -> {16, 8, 2, 12, 1}:
    // 2 swizzle gates (16, 12), 4 DPP gates (8, 2, 1 x2).
    unsigned Ucols[5] = {};
    {
        unsigned tgt[5] = {16, 8, 2, 12, 1};
        unsigned acc = 0;
        // u_k chain => U e_{k-1} = xor of tgt[0..k-1]
        for (int k = 0; k < 5; ++k) { acc ^= tgt[k]; Ucols[k] = acc; }
    }
    // rows of U
    unsigned Urows[5] = {};
    for (int r = 0; r < 5; ++r)
        for (int cc = 0; cc < 5; ++cc)
            Urows[r] |= ((Ucols[cc] >> r) & 1u) << cc;
    // invert U (rows) -> AI = rows of A_lane = U^{-1}
    unsigned MM[5] = {}, AI[5] = {};
    for (int i = 0; i < 5; ++i) { MM[i] = Urows[i]; AI[i] = 1u << i; }
    for (int col = 0; col < 5; ++col) {
        int piv = col;
        while (!((MM[piv] >> col) & 1u)) ++piv;
        unsigned tm = MM[col]; MM[col] = MM[piv]; MM[piv] = tm;
        unsigned ti = AI[col]; AI[col] = AI[piv]; AI[piv] = ti;
        for (int r = 0; r < 5; ++r)
            if (r != col && ((MM[r] >> col) & 1u)) { MM[r] ^= MM[col]; AI[r] ^= AI[col]; }
    }
    // transform gate lane masks (U m), lane rows (A^T row), sign lane masks
    for (int w = 0; w < 10; ++w) {
        unsigned mL = unsigned(c.g[10 + w].laneXor);
        unsigned nm = 0;
        for (int i = 0; i < 5; ++i) if ((mL >> i) & 1u) nm ^= Ucols[i];
        c.g[10 + w].laneXor = int(nm);
        unsigned rL = unsigned(c.g[10 + w].rowL);
        unsigned nr = 0;
        for (int i = 0; i < 5; ++i) if ((rL >> i) & 1u) nr ^= AI[i];
        c.g[10 + w].rowL = int(nr);
    }
    for (int q = 0; q < 10; ++q) {
        unsigned sL = unsigned(c.sgnL[q]);
        unsigned ns = 0;
        for (int i = 0; i < 5; ++i) if ((sL >> i) & 1u) ns ^= AI[i];
        c.sgnL[q] = int(ns);
    }
    // lane-wire selectors: wire w (0..4) at position 5+(4-w): row 4-w of A_lane
    for (int o = 0; o < 5; ++o) c.lsel[o] = int(AI[o]);
    return c;
}

constexpr Circ CC = build_circ();

// Final gate inventory this schedule depends on (computed, then asserted).
static_assert(CC.g[10].laneXor == 1  && CC.g[10].regXor == 0,  "w0");
static_assert(CC.g[11].laneXor == 12 && CC.g[11].regXor == 0,  "w1");
static_assert(CC.g[12].laneXor == 2  && CC.g[12].regXor == 0,  "w2");
static_assert(CC.g[13].laneXor == 8  && CC.g[13].regXor == 0,  "w3");
static_assert(CC.g[14].laneXor == 16 && CC.g[14].regXor == 16, "w4");
static_assert(CC.g[15].laneXor == 0  && CC.g[15].regXor == 24, "w5");
static_assert(CC.g[16].laneXor == 0  && CC.g[16].regXor == 12, "w6");
static_assert(CC.g[17].laneXor == 0  && CC.g[17].regXor == 6,  "w7");
static_assert(CC.g[18].laneXor == 0  && CC.g[18].regXor == 3,  "w8");
static_assert(CC.g[19].laneXor == 1  && CC.g[19].regXor == 1,  "w9");
// Phase-folding relies on these reg rows (unchanged by the basis change).
static_assert(CC.g[10].rowR == 31, "w0 rowR");
static_assert(CC.g[11].rowR == 0,  "w1 rowR");
static_assert(CC.g[12].rowR == 0,  "w2 rowR");
static_assert(CC.g[13].rowR == 0,  "w3 rowR");
static_assert(CC.g[14].rowR == 0,  "w4 rowR");
static_assert(CC.g[15].rowR == 16, "w5 rowR");
static_assert(CC.g[16].rowR == 24, "w6 rowR");
static_assert(CC.g[17].rowR == 28, "w7 rowR");
static_assert(CC.g[18].rowR == 30, "w8 rowR");
static_assert(CC.g[19].rowR == 31, "w9 rowR");

// sign-word xor: sw has the sign in bit 31 (or is 0)
DEVINL float csw(float v, int sw) {
    return __int_as_float(__float_as_int(v) ^ sw);
}

// lane-xor fetch:
//   1,2,3 -> DPP quad_perm;  7 -> DPP row_half_mirror; 8 -> DPP row_ror:8
//   (both proven correct by R7's pass);  else (<32) -> ds_swizzle.
//   All patterns stay within 32-lane halves (samples never mix).
template<int XOR>
DEVINL float fetch(float v, int lane) {
    if constexpr (XOR == 0)      return v;
    else if constexpr (XOR == 1) return __int_as_float(__builtin_amdgcn_update_dpp(0, __float_as_int(v), 0xB1, 0xF, 0xF, true));
    else if constexpr (XOR == 2) return __int_as_float(__builtin_amdgcn_update_dpp(0, __float_as_int(v), 0x4E, 0xF, 0xF, true));
    else if constexpr (XOR == 3) return __int_as_float(__builtin_amdgcn_update_dpp(0, __float_as_int(v), 0x1B, 0xF, 0xF, true));
    else if constexpr (XOR == 7) return __int_as_float(__builtin_amdgcn_update_dpp(0, __float_as_int(v), 0x141, 0xF, 0xF, true));
    else if constexpr (XOR == 8) return __int_as_float(__builtin_amdgcn_update_dpp(0, __float_as_int(v), 0x128, 0xF, 0xF, true));
    else                         return __int_as_float(__builtin_amdgcn_ds_swizzle(__float_as_int(v), 0x1F | (XOR << 10)));
}

// forced packed FMA: a = t*b + a
DEVINL void pk_fma_acc(f32x2& a, f32x2 t, f32x2 b) {
    asm("v_pk_fma_f32 %0, %1, %2, %0" : "+v"(a) : "v"(t), "v"(b));
}

DEVINL f32x2 cmul(f32x2 a, f32x2 b) {
    f32x2 r;
    r.x = a.x * b.x - a.y * b.y;
    r.y = a.x * b.y + a.y * b.x;
    return r;
}

// ---------------------------------------------------------------------------
// Constants, computed once by qprep (wire-indexed; basis-agnostic):
// [0..39]  layer-0 Rot mats (u00r,u00i,u01r,u01i per wire)
// [40..49] layer-1 tan(th/2) per wire
// [50..69] layer-1 (cos(phi/2), -sin(phi/2)) per wire
// [70]     prod_w cos(th_w/2)
// ---------------------------------------------------------------------------
__device__ __attribute__((aligned(16))) float g_cst[80];

__global__ void qprep(const float* __restrict__ qw) {
    int g = threadIdx.x;
    if (g < 10) {
        float phi = qw[g * 3 + 0], th = qw[g * 3 + 1], om = qw[g * 3 + 2];
        float c = cosf(0.5f * th), s = sinf(0.5f * th);
        float apo = 0.5f * (phi + om), amo = 0.5f * (phi - om);
        g_cst[g * 4 + 0] =  cosf(apo) * c;
        g_cst[g * 4 + 1] = -sinf(apo) * c;
        g_cst[g * 4 + 2] = -cosf(amo) * s;
        g_cst[g * 4 + 3] = -sinf(amo) * s;
    } else if (g < 20) {
        int w = g - 10;
        float phi = qw[g * 3 + 0], th = qw[g * 3 + 1];
        float c = cosf(0.5f * th), s = sinf(0.5f * th);
        g_cst[40 + w] = s / c;
        g_cst[50 + w * 2 + 0] =  cosf(0.5f * phi);
        g_cst[50 + w * 2 + 1] = -sinf(0.5f * phi);
    } else if (g == 20) {
        float p = 1.f;
        for (int w = 0; w < 10; ++w) p *= cosf(0.5f * qw[(10 + w) * 3 + 1]);
        g_cst[70] = p;
    }
}

// per-wire embedding factor: |0> --RY(x)--> --Rot(layer0)--> (f0, f1)
DEVINL void wf(const float* cst, float xw, int w, f32x2& f0, f32x2& f1) {
    float h = 0.5f * xw;
    float s = __sinf(h), c = __cosf(h);
    float m0 = cst[w * 4 + 0], m1 = cst[w * 4 + 1], m2 = cst[w * 4 + 2], m3 = cst[w * 4 + 3];
    f0.x =  m0 * c + m2 * s;
    f0.y =  m1 * c + m3 * s;
    f1.x = -m2 * c + m0 * s;
    f1.y =  m3 * c - m1 * s;
}

// Layer-1 RY gate as fast-Givens on packed {re,im}: a' = a +- t*b.
// regXor==0 lane gates: per-register fetch-then-fma (lockstep-safe, no
// staging).  Paired gates (regXor!=0): two temps per pair, fetches first.
template<int W>
DEVINL void apply_gate(f32x2 (&a2)[32], const float* cst, int lane, const int (&sw)[10]) {
    constexpr GC gc = CC.g[10 + W];
    float tt = csw(cst[40 + W], sw[W]);
    f32x2 tp; tp.x = tt;  tp.y = tt;
    f32x2 tn; tn.x = -tt; tn.y = -tt;
    if constexpr (gc.laneXor == 0) {
        #pragma unroll
        for (int r = 0; r < 32; ++r) {
            const int r2 = r ^ gc.regXor;
            if (r < r2) {
                f32x2 old = a2[r];
                const bool sR  = __builtin_popcount(unsigned(gc.rowR & r )) & 1;
                const bool sR2 = __builtin_popcount(unsigned(gc.rowR & r2)) & 1;
                pk_fma_acc(a2[r],  sR  ? tp : tn, a2[r2]);
                pk_fma_acc(a2[r2], sR2 ? tp : tn, old);
            }
        }
    } else if constexpr (gc.regXor == 0) {
        #pragma unroll
        for (int r = 0; r < 32; ++r) {
            f32x2 b;
            b.x = fetch<gc.laneXor>(a2[r].x, lane);
            b.y = fetch<gc.laneXor>(a2[r].y, lane);
            const bool sR = __builtin_popcount(unsigned(gc.rowR & r)) & 1;
            pk_fma_acc(a2[r], sR ? tp : tn, b);
        }
    } else {
        #pragma unroll
        for (int r = 0; r < 32; ++r) {
            const int r2 = r ^ gc.regXor;
            if (r < r2) {
                f32x2 blo, bhi;
                blo.x = fetch<gc.laneXor>(a2[r2].x, lane);
                blo.y = fetch<gc.laneXor>(a2[r2].y, lane);
                bhi.x = fetch<gc.laneXor>(a2[r].x, lane);
                bhi.y = fetch<gc.laneXor>(a2[r].y, lane);
                const bool sR  = __builtin_popcount(unsigned(gc.rowR & r )) & 1;
                const bool sR2 = __builtin_popcount(unsigned(gc.rowR & r2)) & 1;
                pk_fma_acc(a2[r],  sR  ? tp : tn, blo);
                pk_fma_acc(a2[r2], sR2 ? tp : tn, bhi);
            }
        }
    }
}

__global__ __launch_bounds__(256) void qsim(const float* __restrict__ x,
                                            float* __restrict__ out, int B) {
    const float* cst = g_cst;
    int lane = threadIdx.x & 63;
    int l5 = lane & 31;                        // 5-bit lane within the sample
    int b = blockIdx.x * 8 + (threadIdx.x >> 5);   // 2 samples/wave, 8/block
    if (b >= B) return;

    // ---- vectorized x load: 5x dwordx2 (b*40 bytes ≡ 0 mod 8)
    const f32x2* xp = reinterpret_cast<const f32x2*>(x + b * 10);
    f32x2 xv0 = xp[0], xv1 = xp[1], xv2 = xp[2], xv3 = xp[3], xv4 = xp[4];
    float xw[10] = { xv0.x, xv0.y, xv1.x, xv1.y, xv2.x,
                     xv2.y, xv3.x, xv3.y, xv4.x, xv4.y };

    // ---- lane-parity sign words for the layer-1 rows (bit 31 = sign),
    //      rows already transformed to q-space (A^T) at compile time
    int sw_[10];
    #pragma unroll
    for (int w = 0; w < 10; ++w)
        sw_[w] = (__popc(unsigned(l5 & CC.g[10 + w].rowL)) & 1) << 31;

    // ---- reg-wire tables: bit0=w9, bit1=w8, bit2=w7, bit3=w6, bit4=w5
    f32x2 t01[4], t23[4], f5t[2];
    {
        f32x2 a0, a1, b0, b1;
        wf(cst, xw[9], 9, a0, a1);
        wf(cst, xw[8], 8, b0, b1);
        t01[0] = cmul(a0, b0); t01[1] = cmul(a1, b0);
        t01[2] = cmul(a0, b1); t01[3] = cmul(a1, b1);
        wf(cst, xw[7], 7, a0, a1);
        wf(cst, xw[6], 6, b0, b1);
        t23[0] = cmul(a0, b0); t23[1] = cmul(a1, b0);
        t23[2] = cmul(a0, b1); t23[3] = cmul(a1, b1);
        wf(cst, xw[5], 5, f5t[0], f5t[1]);
    }

    // ---- lane-signed RZ(phi) phase constants E_w = (cos, -+sin)
    f32x2 E0; E0.x = cst[50];      E0.y = csw(cst[51], sw_[0]);
    f32x2 E1; E1.x = cst[52];      E1.y = csw(cst[53], sw_[1]);
    f32x2 E2; E2.x = cst[54];      E2.y = csw(cst[55], sw_[2]);
    f32x2 E3; E3.x = cst[56];      E3.y = csw(cst[57], sw_[3]);
    f32x2 E4; E4.x = cst[58];      E4.y = csw(cst[59], sw_[4]);
    f32x2 E5; E5.x = cst[60];      E5.y = csw(cst[61], sw_[5]);
    f32x2 E6; E6.x = cst[62];      E6.y = csw(cst[63], sw_[6]);
    f32x2 E7; E7.x = cst[64];      E7.y = csw(cst[65], sw_[7]);
    f32x2 E8; E8.x = cst[66];      E8.y = csw(cst[67], sw_[8]);
    f32x2 E9; E9.x = cst[68];      E9.y = csw(cst[69], sw_[9]);

    // ---- lane factor: E_A (w1..w4) * cos-product * lane-wire factors
    //      (selectors = parities of l5 vs rows of A_lane; tree-shaped chain)
    f32x2 lf;
    {
        f32x2 p[5];
        #pragma unroll
        for (int jj = 0; jj < 5; ++jj) {
            int w = 4 - jj;                    // wire w <-> selector lsel[jj]
            f32x2 f0, f1;
            wf(cst, xw[w], w, f0, f1);
            int bit = __popc(unsigned(l5 & CC.lsel[jj])) & 1;
            p[jj].x = bit ? f1.x : f0.x;
            p[jj].y = bit ? f1.y : f0.y;
        }
        f32x2 ea = cmul(cmul(E1, E2), cmul(E3, E4));
        float sc = cst[70];
        ea.x *= sc; ea.y *= sc;
        f32x2 q01 = cmul(p[0], p[1]);
        f32x2 q23 = cmul(p[2], p[3]);
        lf = cmul(cmul(q01, q23), cmul(ea, p[4]));
    }

    // ---- fold w5 phase into f5 (bit4); build V/H phase products
    f32x2 f5p[2];
    f5p[0] = cmul(f5t[0], E5);
    { f32x2 e5c; e5c.x = E5.x; e5c.y = -E5.y; f5p[1] = cmul(f5t[1], e5c); }
    f32x2 V00 = cmul(E6, E7);
    f32x2 V01; { f32x2 e7c; e7c.x = E7.x; e7c.y = -E7.y; V01 = cmul(E6, e7c); }
    f32x2 EB = cmul(E9, E0);
    f32x2 H0 = cmul(E8, EB);
    f32x2 H1; { f32x2 ebc; ebc.x = EB.x; ebc.y = -EB.y; H1 = cmul(E8, ebc); }

    // ---- tf[8] = t23[j&3] * f5p[j>>2] * V^{s6,s7}   (j = bits 4,3,2 of r)
    f32x2 tf[8];
    #pragma unroll
    for (int j = 0; j < 8; ++j) {
        f32x2 tA = cmul(t23[j & 3], f5p[j >> 2]);
        const int s6 = ((j >> 2) ^ (j >> 1)) & 1;
        const int s7 = s6 ^ (j & 1);
        f32x2 V;
        V.x = s6 ? (s7 ? V00.x : V01.x) : (s7 ? V01.x : V00.x);
        V.y = s6 ? -(s7 ? V00.y : V01.y) : (s7 ? V01.y : V00.y);
        tf[j] = cmul(tA, V);
    }

    // ---- g4 = lf * t01 ; fold H (index = r&1 = bit0 of v) into g4H[v][conj]
    f32x2 g4H[4][2];
    #pragma unroll
    for (int v = 0; v < 4; ++v) {
        f32x2 g = cmul(lf, t01[v]);
        f32x2 H = (v & 1) ? H1 : H0;
        g4H[v][0] = cmul(g, H);
        f32x2 Hc; Hc.x = H.x; Hc.y = -H.y;
        g4H[v][1] = cmul(g, Hc);
    }
    // amps: conj flag = bit1(v) ^ parity(j)  (all compile-time)
    f32x2 a2[32];
    #pragma unroll
    for (int r = 0; r < 32; ++r) {
        const int v = r & 3, j = (r >> 2) & 7;
        const int sel = ((v >> 1) ^ __builtin_popcount(unsigned(j))) & 1;
        a2[r] = cmul(g4H[v][sel], tf[j]);
    }

    // ---- layer-1 RY gates (commuting); swizzle gates spread apart
    apply_gate<4>(a2, cst, lane, sw_);   // swz16 (reg^16)
    apply_gate<5>(a2, cst, lane, sw_);   // local reg^24
    apply_gate<3>(a2, cst, lane, sw_);   // DPP xor8 (row_ror:8)
    apply_gate<6>(a2, cst, lane, sw_);   // local reg^12
    apply_gate<1>(a2, cst, lane, sw_);   // swz12
    apply_gate<7>(a2, cst, lane, sw_);   // local reg^6
    apply_gate<2>(a2, cst, lane, sw_);   // DPP xor2
    apply_gate<8>(a2, cst, lane, sw_);   // local reg^3
    apply_gate<0>(a2, cst, lane, sw_);   // DPP xor1
    apply_gate<9>(a2, cst, lane, sw_);   // DPP xor1 (reg^1)

    // ---- probabilities + reg-WHT stages 1,2,4,8 (stage 16 pruned into e[q])
    float wv[32];
    #pragma unroll
    for (int r = 0; r < 32; ++r) wv[r] = a2[r].x * a2[r].x + a2[r].y * a2[r].y;
    #pragma unroll
    for (int bS = 1; bS < 16; bS <<= 1) {
        #pragma unroll
        for (int r = 0; r < 32; ++r) {
            if (!(r & bS)) {
                float xvv = wv[r], yv = wv[r | bS];
                wv[r]      = xvv + yv;
                wv[r | bS] = xvv - yv;
            }
        }
    }

    float e[10];
    #pragma unroll
    for (int q = 0; q < 10; ++q) {
        const int R = CC.sgnR[q];
        float num = (R & 16) ? (wv[R ^ 16] - wv[R]) : (wv[R] + wv[R ^ 16]);
        int slq = __popc(unsigned(l5 & CC.sgnL[q])) & 1;
        e[q] = csw(num, slq << 31);
    }

    // ---- lane reduction within each 32-half: DPP quad-reduce, slot-pack to
    //      3, then xor4 (swz) / xor8 (DPP ror8) / xor16 (swz)
    #pragma unroll
    for (int q = 0; q < 10; ++q) {
        e[q] += fetch<1>(e[q], lane);
        e[q] += fetch<2>(e[q], lane);
    }
    int s = l5 & 3;
    bool s1 = (s & 1) != 0, s2 = (s & 2) != 0;
    float v0 = s1 ? e[1] : e[0];
    float u0 = s1 ? e[3] : e[2];
    v0 = s2 ? u0 : v0;
    float v1 = s1 ? e[5] : e[4];
    float u1 = s1 ? e[7] : e[6];
    v1 = s2 ? u1 : v1;
    float v2 = s1 ? e[9] : e[8];

    v0 += fetch<4>(v0, lane);   v1 += fetch<4>(v1, lane);   v2 += fetch<4>(v2, lane);
    v0 += fetch<8>(v0, lane);   v1 += fetch<8>(v1, lane);   v2 += fetch<8>(v2, lane);
    v0 += fetch<16>(v0, lane);  v1 += fetch<16>(v1, lane);  v2 += fetch<16>(v2, lane);

    // lane l5==q holds full sum of e[q] in v_{q>>2} (slot matches l5&3)
    float vo = v0;
    int hi = l5 >> 2;
    vo = (hi == 1) ? v1 : vo;
    vo = (hi == 2) ? v2 : vo;
    if (l5 < 10) out[b * 10 + l5] = vo;
}

extern "C" void kernel_launch(void* const* d_in, const int* in_sizes, int n_in,
                              void* d_out, int out_size, void* d_ws, size_t ws_size,
                              hipStream_t stream) {
    const float* x  = (const float*)d_in[0];
    const float* qw = (const float*)d_in[1];
    float* out = (float*)d_out;
    int B = in_sizes[0] / 10;
    int blocks = (B + 7) / 8;   // 8 samples per 256-thread block (2 per wave)
    hipLaunchKernelGGL(qprep, dim3(1), dim3(64), 0, stream, qw);
    hipLaunchKernelGGL(qsim, dim3(blocks), dim3(256), 0, stream, x, out, B);
}

// Round 9
// 82.606 us; speedup vs baseline: 1.0237x; 1.0055x over previous
//
#include <hip/hip_runtime.h>

#define DEVINL __device__ __forceinline__

typedef float f32x2 __attribute__((ext_vector_type(2)));

// ---------------------------------------------------------------------------
// Compile-time circuit constants via GF(2) linear-map tracking.
// Physical index q (10 bits): bits 9..5 = lane l5 (5 bits), bits 4..0 = reg.
// Lane bit 5 of the hw lane = SAMPLE SELECT (2 samples per wave).
//
// Round-9 (R8 ~ R6 within noise; latency-bound diagnosis: static count
// ~1600 VALU/wave = ~11us issue floor vs ~30us actual):
//  * Local gates in plain C (SSA temporaries): the old pk_fma_acc asm's
//    "+v" forced in-place accumulation -> 128 real v_mov copies/wave for
//    the 4 paired local gates.  SSA renaming removes them and shortens
//    each pair's dependency chain.
//  * j-major amp build: tf[j] folded into the loop, 16-VGPR array gone.
//  * __launch_bounds__(256, 4): cap VGPR at 128 -> >=4 waves/SIMD.
//  * Gates with rowR==0 use only the negated coefficient (skip tp).
// Basis (from R8): w4->swz16(reg^16), w1->swz12, w3->DPP ror8, w2->DPP
// xor2, w0/w9->DPP xor1 (w9 reg^1), w5..w8 reg-local.  All masks/rows
// computed constexpr and static_asserted.
// ---------------------------------------------------------------------------
struct GC { int laneXor, regXor, rowL, rowR; };
struct Circ { GC g[20]; int sgnL[10], sgnR[10]; int lsel[5]; };

constexpr Circ build_circ() {
    Circ c{};
    unsigned A[10] = {};
    for (int i = 0; i < 10; ++i) A[i] = 1u << i;
    for (int w = 0; w < 10; ++w) {
        int pos = 9 - w;
        unsigned m = 1u << pos;
        c.g[w] = GC{ int(m >> 5), int(m & 31u), int(m >> 5), int(m & 31u) };
    }
    // layer 0 CNOT ring, range r=1
    for (int q = 0; q < 10; ++q) { int pc = 9 - q, pt = 9 - ((q + 1) % 10); A[pt] ^= A[pc]; }
    // invert A over GF(2)
    unsigned M[10] = {}, Inv[10] = {};
    for (int i = 0; i < 10; ++i) { M[i] = A[i]; Inv[i] = 1u << i; }
    for (int col = 0; col < 10; ++col) {
        int piv = col;
        while (!((M[piv] >> col) & 1u)) ++piv;
        unsigned tm = M[col]; M[col] = M[piv]; M[piv] = tm;
        unsigned ti = Inv[col]; Inv[col] = Inv[piv]; Inv[piv] = ti;
        for (int r = 0; r < 10; ++r)
            if (r != col && ((M[r] >> col) & 1u)) { M[r] ^= M[col]; Inv[r] ^= Inv[col]; }
    }
    // layer 1 Rot gates in p-space (5/5 split): m = A^{-1} e_pos, row = A[pos]
    for (int w = 0; w < 10; ++w) {
        int pos = 9 - w;
        unsigned m = 0;
        for (int i = 0; i < 10; ++i) m |= ((Inv[i] >> pos) & 1u) << i;
        unsigned row = A[pos];
        c.g[10 + w] = GC{ int(m >> 5), int(m & 31u), int(row >> 5), int(row & 31u) };
    }
    // layer 1 CNOT ring, range r=2
    for (int q = 0; q < 10; ++q) { int pc = 9 - q, pt = 9 - ((q + 2) % 10); A[pt] ^= A[pc]; }
    for (int q = 0; q < 10; ++q) { unsigned row = A[9 - q]; c.sgnL[q] = int(row >> 5); c.sgnR[q] = int(row & 31u); }

    // ---- basis change on the 5 lane bits -------------------------------
    // Lane-parts of the lane-involved gate masks form the chain
    // u1={b0}(w4), u2={b0,b1}(w3), u3={b1,b2}(w2), u4={b2,b3}(w1),
    // u5={b3,b4}(w0 AND w9, doubled).  Map u1..u5 -> {16, 8, 2, 12, 1}.
    unsigned Ucols[5] = {};
    {
        unsigned tgt[5] = {16, 8, 2, 12, 1};
        unsigned acc = 0;
        for (int k = 0; k < 5; ++k) { acc ^= tgt[k]; Ucols[k] = acc; }
    }
    unsigned Urows[5] = {};
    for (int r = 0; r < 5; ++r)
        for (int cc = 0; cc < 5; ++cc)
            Urows[r] |= ((Ucols[cc] >> r) & 1u) << cc;
    unsigned MM[5] = {}, AI[5] = {};
    for (int i = 0; i < 5; ++i) { MM[i] = Urows[i]; AI[i] = 1u << i; }
    for (int col = 0; col < 5; ++col) {
        int piv = col;
        while (!((MM[piv] >> col) & 1u)) ++piv;
        unsigned tm = MM[col]; MM[col] = MM[piv]; MM[piv] = tm;
        unsigned ti = AI[col]; AI[col] = AI[piv]; AI[piv] = ti;
        for (int r = 0; r < 5; ++r)
            if (r != col && ((MM[r] >> col) & 1u)) { MM[r] ^= MM[col]; AI[r] ^= AI[col]; }
    }
    for (int w = 0; w < 10; ++w) {
        unsigned mL = unsigned(c.g[10 + w].laneXor);
        unsigned nm = 0;
        for (int i = 0; i < 5; ++i) if ((mL >> i) & 1u) nm ^= Ucols[i];
        c.g[10 + w].laneXor = int(nm);
        unsigned rL = unsigned(c.g[10 + w].rowL);
        unsigned nr = 0;
        for (int i = 0; i < 5; ++i) if ((rL >> i) & 1u) nr ^= AI[i];
        c.g[10 + w].rowL = int(nr);
    }
    for (int q = 0; q < 10; ++q) {
        unsigned sL = unsigned(c.sgnL[q]);
        unsigned ns = 0;
        for (int i = 0; i < 5; ++i) if ((sL >> i) & 1u) ns ^= AI[i];
        c.sgnL[q] = int(ns);
    }
    for (int o = 0; o < 5; ++o) c.lsel[o] = int(AI[o]);
    return c;
}

constexpr Circ CC = build_circ();

// Final gate inventory this schedule depends on (computed, then asserted).
static_assert(CC.g[10].laneXor == 1  && CC.g[10].regXor == 0,  "w0");
static_assert(CC.g[11].laneXor == 12 && CC.g[11].regXor == 0,  "w1");
static_assert(CC.g[12].laneXor == 2  && CC.g[12].regXor == 0,  "w2");
static_assert(CC.g[13].laneXor == 8  && CC.g[13].regXor == 0,  "w3");
static_assert(CC.g[14].laneXor == 16 && CC.g[14].regXor == 16, "w4");
static_assert(CC.g[15].laneXor == 0  && CC.g[15].regXor == 24, "w5");
static_assert(CC.g[16].laneXor == 0  && CC.g[16].regXor == 12, "w6");
static_assert(CC.g[17].laneXor == 0  && CC.g[17].regXor == 6,  "w7");
static_assert(CC.g[18].laneXor == 0  && CC.g[18].regXor == 3,  "w8");
static_assert(CC.g[19].laneXor == 1  && CC.g[19].regXor == 1,  "w9");
// Phase-folding relies on these reg rows (unchanged by the basis change).
static_assert(CC.g[10].rowR == 31, "w0 rowR");
static_assert(CC.g[11].rowR == 0,  "w1 rowR");
static_assert(CC.g[12].rowR == 0,  "w2 rowR");
static_assert(CC.g[13].rowR == 0,  "w3 rowR");
static_assert(CC.g[14].rowR == 0,  "w4 rowR");
static_assert(CC.g[15].rowR == 16, "w5 rowR");
static_assert(CC.g[16].rowR == 24, "w6 rowR");
static_assert(CC.g[17].rowR == 28, "w7 rowR");
static_assert(CC.g[18].rowR == 30, "w8 rowR");
static_assert(CC.g[19].rowR == 31, "w9 rowR");
// w0 rowR=31: sign varies per reg?  popcount parity vs pair mask: w0 has
// regXor==0, so rowR only sets the per-reg sign; handled generically below.

// sign-word xor: sw has the sign in bit 31 (or is 0)
DEVINL float csw(float v, int sw) {
    return __int_as_float(__float_as_int(v) ^ sw);
}

// lane-xor fetch:
//   1,2,3 -> DPP quad_perm; 8 -> DPP row_ror:8 (proven R7/R8);
//   else (<32) -> ds_swizzle.  All patterns stay within 32-lane halves.
template<int XOR>
DEVINL float fetch(float v, int lane) {
    if constexpr (XOR == 0)      return v;
    else if constexpr (XOR == 1) return __int_as_float(__builtin_amdgcn_update_dpp(0, __float_as_int(v), 0xB1, 0xF, 0xF, true));
    else if constexpr (XOR == 2) return __int_as_float(__builtin_amdgcn_update_dpp(0, __float_as_int(v), 0x4E, 0xF, 0xF, true));
    else if constexpr (XOR == 3) return __int_as_float(__builtin_amdgcn_update_dpp(0, __float_as_int(v), 0x1B, 0xF, 0xF, true));
    else if constexpr (XOR == 8) return __int_as_float(__builtin_amdgcn_update_dpp(0, __float_as_int(v), 0x128, 0xF, 0xF, true));
    else                         return __int_as_float(__builtin_amdgcn_ds_swizzle(__float_as_int(v), 0x1F | (XOR << 10)));
}

// forced packed FMA for in-place accumulate against a TEMP operand
// (no copies needed: b is a staging temp, a is genuinely accumulated)
DEVINL void pk_fma_acc(f32x2& a, f32x2 t, f32x2 b) {
    asm("v_pk_fma_f32 %0, %1, %2, %0" : "+v"(a) : "v"(t), "v"(b));
}

DEVINL f32x2 cmul(f32x2 a, f32x2 b) {
    f32x2 r;
    r.x = a.x * b.x - a.y * b.y;
    r.y = a.x * b.y + a.y * b.x;
    return r;
}

// ---------------------------------------------------------------------------
// Constants, computed once by qprep (wire-indexed; basis-agnostic):
// [0..39]  layer-0 Rot mats (u00r,u00i,u01r,u01i per wire)
// [40..49] layer-1 tan(th/2) per wire
// [50..69] layer-1 (cos(phi/2), -sin(phi/2)) per wire
// [70]     prod_w cos(th_w/2)
// ---------------------------------------------------------------------------
__device__ __attribute__((aligned(16))) float g_cst[80];

__global__ void qprep(const float* __restrict__ qw) {
    int g = threadIdx.x;
    if (g < 10) {
        float phi = qw[g * 3 + 0], th = qw[g * 3 + 1], om = qw[g * 3 + 2];
        float c = cosf(0.5f * th), s = sinf(0.5f * th);
        float apo = 0.5f * (phi + om), amo = 0.5f * (phi - om);
        g_cst[g * 4 + 0] =  cosf(apo) * c;
        g_cst[g * 4 + 1] = -sinf(apo) * c;
        g_cst[g * 4 + 2] = -cosf(amo) * s;
        g_cst[g * 4 + 3] = -sinf(amo) * s;
    } else if (g < 20) {
        int w = g - 10;
        float phi = qw[g * 3 + 0], th = qw[g * 3 + 1];
        float c = cosf(0.5f * th), s = sinf(0.5f * th);
        g_cst[40 + w] = s / c;
        g_cst[50 + w * 2 + 0] =  cosf(0.5f * phi);
        g_cst[50 + w * 2 + 1] = -sinf(0.5f * phi);
    } else if (g == 20) {
        float p = 1.f;
        for (int w = 0; w < 10; ++w) p *= cosf(0.5f * qw[(10 + w) * 3 + 1]);
        g_cst[70] = p;
    }
}

// per-wire embedding factor: |0> --RY(x)--> --Rot(layer0)--> (f0, f1)
DEVINL void wf(const float* cst, float xw, int w, f32x2& f0, f32x2& f1) {
    float h = 0.5f * xw;
    float s = __sinf(h), c = __cosf(h);
    float m0 = cst[w * 4 + 0], m1 = cst[w * 4 + 1], m2 = cst[w * 4 + 2], m3 = cst[w * 4 + 3];
    f0.x =  m0 * c + m2 * s;
    f0.y =  m1 * c + m3 * s;
    f1.x = -m2 * c + m0 * s;
    f1.y =  m3 * c - m1 * s;
}

// Layer-1 RY gate as fast-Givens on packed {re,im}: a' = a +- t*b.
//  * local paired gates: plain C (SSA renaming, no forced copies)
//  * lane-fetch gates regXor==0: builtin fetch + in-place pk_fma (b = temp)
//  * paired lane gates: stage both fetches, then in-place pk_fma
template<int W>
DEVINL void apply_gate(f32x2 (&a2)[32], const float* cst, int lane, const int (&sw)[10]) {
    constexpr GC gc = CC.g[10 + W];
    float tt = csw(cst[40 + W], sw[W]);
    if constexpr (gc.laneXor == 0) {
        f32x2 tp; tp.x = tt;  tp.y = tt;
        f32x2 tn; tn.x = -tt; tn.y = -tt;
        #pragma unroll
        for (int r = 0; r < 32; ++r) {
            const int r2 = r ^ gc.regXor;
            if (r < r2) {
                const bool sR  = __builtin_popcount(unsigned(gc.rowR & r )) & 1;
                const bool sR2 = __builtin_popcount(unsigned(gc.rowR & r2)) & 1;
                f32x2 ca = a2[r], cb = a2[r2];
                f32x2 na = ca + (sR  ? tp : tn) * cb;   // -> v_pk_fma, SSA
                f32x2 nb = cb + (sR2 ? tp : tn) * ca;
                a2[r] = na; a2[r2] = nb;
            }
        }
    } else if constexpr (gc.regXor == 0) {
        f32x2 tp; tp.x = tt;  tp.y = tt;
        f32x2 tn; tn.x = -tt; tn.y = -tt;
        #pragma unroll
        for (int r = 0; r < 32; ++r) {
            f32x2 b;
            b.x = fetch<gc.laneXor>(a2[r].x, lane);
            b.y = fetch<gc.laneXor>(a2[r].y, lane);
            const bool sR = __builtin_popcount(unsigned(gc.rowR & r)) & 1;
            pk_fma_acc(a2[r], sR ? tp : tn, b);
        }
    } else {
        f32x2 tp; tp.x = tt;  tp.y = tt;
        f32x2 tn; tn.x = -tt; tn.y = -tt;
        #pragma unroll
        for (int r = 0; r < 32; ++r) {
            const int r2 = r ^ gc.regXor;
            if (r < r2) {
                f32x2 blo, bhi;
                blo.x = fetch<gc.laneXor>(a2[r2].x, lane);
                blo.y = fetch<gc.laneXor>(a2[r2].y, lane);
                bhi.x = fetch<gc.laneXor>(a2[r].x, lane);
                bhi.y = fetch<gc.laneXor>(a2[r].y, lane);
                const bool sR  = __builtin_popcount(unsigned(gc.rowR & r )) & 1;
                const bool sR2 = __builtin_popcount(unsigned(gc.rowR & r2)) & 1;
                pk_fma_acc(a2[r],  sR  ? tp : tn, blo);
                pk_fma_acc(a2[r2], sR2 ? tp : tn, bhi);
            }
        }
    }
}

__global__ __launch_bounds__(256, 4) void qsim(const float* __restrict__ x,
                                               float* __restrict__ out, int B) {
    const float* cst = g_cst;
    int lane = threadIdx.x & 63;
    int l5 = lane & 31;                        // 5-bit lane within the sample
    int b = blockIdx.x * 8 + (threadIdx.x >> 5);   // 2 samples/wave, 8/block
    if (b >= B) return;

    // ---- vectorized x load: 5x dwordx2 (b*40 bytes ≡ 0 mod 8)
    const f32x2* xp = reinterpret_cast<const f32x2*>(x + b * 10);
    f32x2 xv0 = xp[0], xv1 = xp[1], xv2 = xp[2], xv3 = xp[3], xv4 = xp[4];
    float xw[10] = { xv0.x, xv0.y, xv1.x, xv1.y, xv2.x,
                     xv2.y, xv3.x, xv3.y, xv4.x, xv4.y };

    // ---- lane-parity sign words for the layer-1 rows (bit 31 = sign),
    //      rows already transformed to q-space (A^T) at compile time
    int sw_[10];
    #pragma unroll
    for (int w = 0; w < 10; ++w)
        sw_[w] = (__popc(unsigned(l5 & CC.g[10 + w].rowL)) & 1) << 31;

    // ---- reg-wire tables: bit0=w9, bit1=w8, bit2=w7, bit3=w6, bit4=w5
    f32x2 t01[4], t23[4], f5t[2];
    {
        f32x2 a0, a1, b0, b1;
        wf(cst, xw[9], 9, a0, a1);
        wf(cst, xw[8], 8, b0, b1);
        t01[0] = cmul(a0, b0); t01[1] = cmul(a1, b0);
        t01[2] = cmul(a0, b1); t01[3] = cmul(a1, b1);
        wf(cst, xw[7], 7, a0, a1);
        wf(cst, xw[6], 6, b0, b1);
        t23[0] = cmul(a0, b0); t23[1] = cmul(a1, b0);
        t23[2] = cmul(a0, b1); t23[3] = cmul(a1, b1);
        wf(cst, xw[5], 5, f5t[0], f5t[1]);
    }

    // ---- lane-signed RZ(phi) phase constants E_w = (cos, -+sin)
    f32x2 E0; E0.x = cst[50];      E0.y = csw(cst[51], sw_[0]);
    f32x2 E1; E1.x = cst[52];      E1.y = csw(cst[53], sw_[1]);
    f32x2 E2; E2.x = cst[54];      E2.y = csw(cst[55], sw_[2]);
    f32x2 E3; E3.x = cst[56];      E3.y = csw(cst[57], sw_[3]);
    f32x2 E4; E4.x = cst[58];      E4.y = csw(cst[59], sw_[4]);
    f32x2 E5; E5.x = cst[60];      E5.y = csw(cst[61], sw_[5]);
    f32x2 E6; E6.x = cst[62];      E6.y = csw(cst[63], sw_[6]);
    f32x2 E7; E7.x = cst[64];      E7.y = csw(cst[65], sw_[7]);
    f32x2 E8; E8.x = cst[66];      E8.y = csw(cst[67], sw_[8]);
    f32x2 E9; E9.x = cst[68];      E9.y = csw(cst[69], sw_[9]);

    // ---- lane factor: E_A (w1..w4) * cos-product * lane-wire factors
    f32x2 lf;
    {
        f32x2 p[5];
        #pragma unroll
        for (int jj = 0; jj < 5; ++jj) {
            int w = 4 - jj;                    // wire w <-> selector lsel[jj]
            f32x2 f0, f1;
            wf(cst, xw[w], w, f0, f1);
            int bit = __popc(unsigned(l5 & CC.lsel[jj])) & 1;
            p[jj].x = bit ? f1.x : f0.x;
            p[jj].y = bit ? f1.y : f0.y;
        }
        f32x2 ea = cmul(cmul(E1, E2), cmul(E3, E4));
        float sc = cst[70];
        ea.x *= sc; ea.y *= sc;
        f32x2 q01 = cmul(p[0], p[1]);
        f32x2 q23 = cmul(p[2], p[3]);
        lf = cmul(cmul(q01, q23), cmul(ea, p[4]));
    }

    // ---- fold w5 phase into f5 (bit4); build V/H phase products
    f32x2 f5p[2];
    f5p[0] = cmul(f5t[0], E5);
    { f32x2 e5c; e5c.x = E5.x; e5c.y = -E5.y; f5p[1] = cmul(f5t[1], e5c); }
    f32x2 V00 = cmul(E6, E7);
    f32x2 V01; { f32x2 e7c; e7c.x = E7.x; e7c.y = -E7.y; V01 = cmul(E6, e7c); }
    f32x2 EB = cmul(E9, E0);
    f32x2 H0 = cmul(E8, EB);
    f32x2 H1; { f32x2 ebc; ebc.x = EB.x; ebc.y = -EB.y; H1 = cmul(E8, ebc); }

    // ---- g4H[v][conj]: lf * t01[v] * (H(v&1) or conj)
    f32x2 g4H[4][2];
    #pragma unroll
    for (int v = 0; v < 4; ++v) {
        f32x2 g = cmul(lf, t01[v]);
        f32x2 H = (v & 1) ? H1 : H0;
        g4H[v][0] = cmul(g, H);
        f32x2 Hc; Hc.x = H.x; Hc.y = -H.y;
        g4H[v][1] = cmul(g, Hc);
    }

    // ---- amps, j-major (tf folded into the loop; no tf[8] array)
    f32x2 a2[32];
    #pragma unroll
    for (int j = 0; j < 8; ++j) {
        f32x2 tA = cmul(t23[j & 3], f5p[j >> 2]);
        const int s6 = ((j >> 2) ^ (j >> 1)) & 1;
        const int s7 = s6 ^ (j & 1);
        f32x2 V;
        V.x = s6 ? (s7 ? V00.x : V01.x) : (s7 ? V01.x : V00.x);
        V.y = s6 ? -(s7 ? V00.y : V01.y) : (s7 ? V01.y : V00.y);
        f32x2 tfj = cmul(tA, V);
        const int pj = __builtin_popcount(unsigned(j)) & 1;
        #pragma unroll
        for (int v = 0; v < 4; ++v) {
            const int sel = ((v >> 1) ^ pj) & 1;
            a2[(j << 2) | v] = cmul(g4H[v][sel], tfj);
        }
    }

    // ---- layer-1 RY gates (commuting); swizzle gates spread apart
    apply_gate<4>(a2, cst, lane, sw_);   // swz16 (reg^16)
    apply_gate<5>(a2, cst, lane, sw_);   // local reg^24
    apply_gate<3>(a2, cst, lane, sw_);   // DPP xor8 (row_ror:8)
    apply_gate<6>(a2, cst, lane, sw_);   // local reg^12
    apply_gate<1>(a2, cst, lane, sw_);   // swz12
    apply_gate<7>(a2, cst, lane, sw_);   // local reg^6
    apply_gate<2>(a2, cst, lane, sw_);   // DPP xor2
    apply_gate<8>(a2, cst, lane, sw_);   // local reg^3
    apply_gate<0>(a2, cst, lane, sw_);   // DPP xor1
    apply_gate<9>(a2, cst, lane, sw_);   // DPP xor1 (reg^1)

    // ---- probabilities + reg-WHT stages 1,2,4,8 (stage 16 pruned into e[q])
    float wv[32];
    #pragma unroll
    for (int r = 0; r < 32; ++r) wv[r] = a2[r].x * a2[r].x + a2[r].y * a2[r].y;
    #pragma unroll
    for (int bS = 1; bS < 16; bS <<= 1) {
        #pragma unroll
        for (int r = 0; r < 32; ++r) {
            if (!(r & bS)) {
                float xvv = wv[r], yv = wv[r | bS];
                wv[r]      = xvv + yv;
                wv[r | bS] = xvv - yv;
            }
        }
    }

    float e[10];
    #pragma unroll
    for (int q = 0; q < 10; ++q) {
        const int R = CC.sgnR[q];
        float num = (R & 16) ? (wv[R ^ 16] - wv[R]) : (wv[R] + wv[R ^ 16]);
        int slq = __popc(unsigned(l5 & CC.sgnL[q])) & 1;
        e[q] = csw(num, slq << 31);
    }

    // ---- lane reduction within each 32-half: DPP quad-reduce, slot-pack to
    //      3, then xor4 (swz) / xor8 (DPP ror8) / xor16 (swz)
    #pragma unroll
    for (int q = 0; q < 10; ++q) {
        e[q] += fetch<1>(e[q], lane);
        e[q] += fetch<2>(e[q], lane);
    }
    int s = l5 & 3;
    bool s1 = (s & 1) != 0, s2 = (s & 2) != 0;
    float v0 = s1 ? e[1] : e[0];
    float u0 = s1 ? e[3] : e[2];
    v0 = s2 ? u0 : v0;
    float v1 = s1 ? e[5] : e[4];
    float u1 = s1 ? e[7] : e[6];
    v1 = s2 ? u1 : v1;
    float v2 = s1 ? e[9] : e[8];

    v0 += fetch<4>(v0, lane);   v1 += fetch<4>(v1, lane);   v2 += fetch<4>(v2, lane);
    v0 += fetch<8>(v0, lane);   v1 += fetch<8>(v1, lane);   v2 += fetch<8>(v2, lane);
    v0 += fetch<16>(v0, lane);  v1 += fetch<16>(v1, lane);  v2 += fetch<16>(v2, lane);

    // lane l5==q holds full sum of e[q] in v_{q>>2} (slot matches l5&3)
    float vo = v0;
    int hi = l5 >> 2;
    vo = (hi == 1) ? v1 : vo;
    vo = (hi == 2) ? v2 : vo;
    if (l5 < 10) out[b * 10 + l5] = vo;
}

extern "C" void kernel_launch(void* const* d_in, const int* in_sizes, int n_in,
                              void* d_out, int out_size, void* d_ws, size_t ws_size,
                              hipStream_t stream) {
    const float* x  = (const float*)d_in[0];
    const float* qw = (const float*)d_in[1];
    float* out = (float*)d_out;
    int B = in_sizes[0] / 10;
    int blocks = (B + 7) / 8;   // 8 samples per 256-thread block (2 per wave)
    hipLaunchKernelGGL(qprep, dim3(1), dim3(64), 0, stream, qw);
    hipLaunchKernelGGL(qsim, dim3(blocks), dim3(256), 0, stream, x, out, B);
}

// Round 10
// 81.864 us; speedup vs baseline: 1.0330x; 1.0091x over previous
//
#include <hip/hip_runtime.h>

#define DEVINL __device__ __forceinline__

typedef float f32x2 __attribute__((ext_vector_type(2)));

// ---------------------------------------------------------------------------
// Compile-time circuit constants via GF(2) linear-map tracking.
// Physical index q (10 bits): bits 9..5 = lane l5 (5 bits), bits 4..0 = reg.
// Lane bit 5 of the hw lane = SAMPLE SELECT (2 samples per wave).
//
// Round-10 (R9 post-mortem: __launch_bounds__(256,4) clamped VGPR to 64 --
// the 64-f32 amplitude state CANNOT fit -> spill to scratch, visible as
// WRITE_SIZE 15.4MB (24x the output) and FETCH 4.4MB; qsim 40 -> 43us):
//  * Clamp removed: plain __launch_bounds__(256).  Scratch traffic -> 0.
//  * Honest pressure reduction instead:
//     - sw_[10] sign-word array deleted; signs recomputed per use (3 VALU
//       each, frees 10 whole-kernel-live regs)
//     - E-phase products built cumulatively (peak 4 regs, not 20)
//     - j-major amp build (no tf[8] array), SSA local gates (from R9)
// Basis (R8): w4->swz16(reg^16), w1->swz12, w3->DPP ror8, w2->DPP xor2,
// w0/w9->DPP xor1 (w9 reg^1), w5..w8 reg-local.  Masks/rows constexpr and
// static_asserted.
// ---------------------------------------------------------------------------
struct GC { int laneXor, regXor, rowL, rowR; };
struct Circ { GC g[20]; int sgnL[10], sgnR[10]; int lsel[5]; };

constexpr Circ build_circ() {
    Circ c{};
    unsigned A[10] = {};
    for (int i = 0; i < 10; ++i) A[i] = 1u << i;
    for (int w = 0; w < 10; ++w) {
        int pos = 9 - w;
        unsigned m = 1u << pos;
        c.g[w] = GC{ int(m >> 5), int(m & 31u), int(m >> 5), int(m & 31u) };
    }
    // layer 0 CNOT ring, range r=1
    for (int q = 0; q < 10; ++q) { int pc = 9 - q, pt = 9 - ((q + 1) % 10); A[pt] ^= A[pc]; }
    // invert A over GF(2)
    unsigned M[10] = {}, Inv[10] = {};
    for (int i = 0; i < 10; ++i) { M[i] = A[i]; Inv[i] = 1u << i; }
    for (int col = 0; col < 10; ++col) {
        int piv = col;
        while (!((M[piv] >> col) & 1u)) ++piv;
        unsigned tm = M[col]; M[col] = M[piv]; M[piv] = tm;
        unsigned ti = Inv[col]; Inv[col] = Inv[piv]; Inv[piv] = ti;
        for (int r = 0; r < 10; ++r)
            if (r != col && ((M[r] >> col) & 1u)) { M[r] ^= M[col]; Inv[r] ^= Inv[col]; }
    }
    // layer 1 Rot gates in p-space (5/5 split): m = A^{-1} e_pos, row = A[pos]
    for (int w = 0; w < 10; ++w) {
        int pos = 9 - w;
        unsigned m = 0;
        for (int i = 0; i < 10; ++i) m |= ((Inv[i] >> pos) & 1u) << i;
        unsigned row = A[pos];
        c.g[10 + w] = GC{ int(m >> 5), int(m & 31u), int(row >> 5), int(row & 31u) };
    }
    // layer 1 CNOT ring, range r=2
    for (int q = 0; q < 10; ++q) { int pc = 9 - q, pt = 9 - ((q + 2) % 10); A[pt] ^= A[pc]; }
    for (int q = 0; q < 10; ++q) { unsigned row = A[9 - q]; c.sgnL[q] = int(row >> 5); c.sgnR[q] = int(row & 31u); }

    // ---- basis change on the 5 lane bits -------------------------------
    // u1={b0}(w4), u2={b0,b1}(w3), u3={b1,b2}(w2), u4={b2,b3}(w1),
    // u5={b3,b4}(w0 AND w9, doubled).  Map u1..u5 -> {16, 8, 2, 12, 1}.
    unsigned Ucols[5] = {};
    {
        unsigned tgt[5] = {16, 8, 2, 12, 1};
        unsigned acc = 0;
        for (int k = 0; k < 5; ++k) { acc ^= tgt[k]; Ucols[k] = acc; }
    }
    unsigned Urows[5] = {};
    for (int r = 0; r < 5; ++r)
        for (int cc = 0; cc < 5; ++cc)
            Urows[r] |= ((Ucols[cc] >> r) & 1u) << cc;
    unsigned MM[5] = {}, AI[5] = {};
    for (int i = 0; i < 5; ++i) { MM[i] = Urows[i]; AI[i] = 1u << i; }
    for (int col = 0; col < 5; ++col) {
        int piv = col;
        while (!((MM[piv] >> col) & 1u)) ++piv;
        unsigned tm = MM[col]; MM[col] = MM[piv]; MM[piv] = tm;
        unsigned ti = AI[col]; AI[col] = AI[piv]; AI[piv] = ti;
        for (int r = 0; r < 5; ++r)
            if (r != col && ((MM[r] >> col) & 1u)) { MM[r] ^= MM[col]; AI[r] ^= AI[col]; }
    }
    for (int w = 0; w < 10; ++w) {
        unsigned mL = unsigned(c.g[10 + w].laneXor);
        unsigned nm = 0;
        for (int i = 0; i < 5; ++i) if ((mL >> i) & 1u) nm ^= Ucols[i];
        c.g[10 + w].laneXor = int(nm);
        unsigned rL = unsigned(c.g[10 + w].rowL);
        unsigned nr = 0;
        for (int i = 0; i < 5; ++i) if ((rL >> i) & 1u) nr ^= AI[i];
        c.g[10 + w].rowL = int(nr);
    }
    for (int q = 0; q < 10; ++q) {
        unsigned sL = unsigned(c.sgnL[q]);
        unsigned ns = 0;
        for (int i = 0; i < 5; ++i) if ((sL >> i) & 1u) ns ^= AI[i];
        c.sgnL[q] = int(ns);
    }
    for (int o = 0; o < 5; ++o) c.lsel[o] = int(AI[o]);
    return c;
}

constexpr Circ CC = build_circ();

// Final gate inventory this schedule depends on (computed, then asserted).
static_assert(CC.g[10].laneXor == 1  && CC.g[10].regXor == 0,  "w0");
static_assert(CC.g[11].laneXor == 12 && CC.g[11].regXor == 0,  "w1");
static_assert(CC.g[12].laneXor == 2  && CC.g[12].regXor == 0,  "w2");
static_assert(CC.g[13].laneXor == 8  && CC.g[13].regXor == 0,  "w3");
static_assert(CC.g[14].laneXor == 16 && CC.g[14].regXor == 16, "w4");
static_assert(CC.g[15].laneXor == 0  && CC.g[15].regXor == 24, "w5");
static_assert(CC.g[16].laneXor == 0  && CC.g[16].regXor == 12, "w6");
static_assert(CC.g[17].laneXor == 0  && CC.g[17].regXor == 6,  "w7");
static_assert(CC.g[18].laneXor == 0  && CC.g[18].regXor == 3,  "w8");
static_assert(CC.g[19].laneXor == 1  && CC.g[19].regXor == 1,  "w9");
static_assert(CC.g[10].rowR == 31, "w0 rowR");
static_assert(CC.g[11].rowR == 0,  "w1 rowR");
static_assert(CC.g[12].rowR == 0,  "w2 rowR");
static_assert(CC.g[13].rowR == 0,  "w3 rowR");
static_assert(CC.g[14].rowR == 0,  "w4 rowR");
static_assert(CC.g[15].rowR == 16, "w5 rowR");
static_assert(CC.g[16].rowR == 24, "w6 rowR");
static_assert(CC.g[17].rowR == 28, "w7 rowR");
static_assert(CC.g[18].rowR == 30, "w8 rowR");
static_assert(CC.g[19].rowR == 31, "w9 rowR");

// sign-word xor: sw has the sign in bit 31 (or is 0)
DEVINL float csw(float v, int sw) {
    return __int_as_float(__float_as_int(v) ^ sw);
}
// lane-parity sign word for a rowL mask (recomputed per use; frees regs)
DEVINL int sgnw(int l5, int rowL) {
    return (__popc(unsigned(l5 & rowL)) & 1) << 31;
}

// lane-xor fetch:
//   1,2,3 -> DPP quad_perm; 8 -> DPP row_ror:8 (proven R7/R8);
//   else (<32) -> ds_swizzle.  All patterns stay within 32-lane halves.
template<int XOR>
DEVINL float fetch(float v) {
    if constexpr (XOR == 0)      return v;
    else if constexpr (XOR == 1) return __int_as_float(__builtin_amdgcn_update_dpp(0, __float_as_int(v), 0xB1, 0xF, 0xF, true));
    else if constexpr (XOR == 2) return __int_as_float(__builtin_amdgcn_update_dpp(0, __float_as_int(v), 0x4E, 0xF, 0xF, true));
    else if constexpr (XOR == 3) return __int_as_float(__builtin_amdgcn_update_dpp(0, __float_as_int(v), 0x1B, 0xF, 0xF, true));
    else if constexpr (XOR == 8) return __int_as_float(__builtin_amdgcn_update_dpp(0, __float_as_int(v), 0x128, 0xF, 0xF, true));
    else                         return __int_as_float(__builtin_amdgcn_ds_swizzle(__float_as_int(v), 0x1F | (XOR << 10)));
}

// forced packed FMA for in-place accumulate against a TEMP operand
DEVINL void pk_fma_acc(f32x2& a, f32x2 t, f32x2 b) {
    asm("v_pk_fma_f32 %0, %1, %2, %0" : "+v"(a) : "v"(t), "v"(b));
}

DEVINL f32x2 cmul(f32x2 a, f32x2 b) {
    f32x2 r;
    r.x = a.x * b.x - a.y * b.y;
    r.y = a.x * b.y + a.y * b.x;
    return r;
}

// ---------------------------------------------------------------------------
// Constants, computed once by qprep (wire-indexed; basis-agnostic):
// [0..39]  layer-0 Rot mats (u00r,u00i,u01r,u01i per wire)
// [40..49] layer-1 tan(th/2) per wire
// [50..69] layer-1 (cos(phi/2), -sin(phi/2)) per wire
// [70]     prod_w cos(th_w/2)
// ---------------------------------------------------------------------------
__device__ __attribute__((aligned(16))) float g_cst[80];

__global__ void qprep(const float* __restrict__ qw) {
    int g = threadIdx.x;
    if (g < 10) {
        float phi = qw[g * 3 + 0], th = qw[g * 3 + 1], om = qw[g * 3 + 2];
        float c = cosf(0.5f * th), s = sinf(0.5f * th);
        float apo = 0.5f * (phi + om), amo = 0.5f * (phi - om);
        g_cst[g * 4 + 0] =  cosf(apo) * c;
        g_cst[g * 4 + 1] = -sinf(apo) * c;
        g_cst[g * 4 + 2] = -cosf(amo) * s;
        g_cst[g * 4 + 3] = -sinf(amo) * s;
    } else if (g < 20) {
        int w = g - 10;
        float phi = qw[g * 3 + 0], th = qw[g * 3 + 1];
        float c = cosf(0.5f * th), s = sinf(0.5f * th);
        g_cst[40 + w] = s / c;
        g_cst[50 + w * 2 + 0] =  cosf(0.5f * phi);
        g_cst[50 + w * 2 + 1] = -sinf(0.5f * phi);
    } else if (g == 20) {
        float p = 1.f;
        for (int w = 0; w < 10; ++w) p *= cosf(0.5f * qw[(10 + w) * 3 + 1]);
        g_cst[70] = p;
    }
}

// lane-signed RZ(phi) phase constant E_w = (cos, +-sin), sign from gate rowL
DEVINL f32x2 mkE(const float* cst, int w, int l5) {
    f32x2 E;
    E.x = cst[50 + w * 2];
    E.y = csw(cst[50 + w * 2 + 1], sgnw(l5, CC.g[10 + w].rowL));
    return E;
}

// per-wire embedding factor: |0> --RY(x)--> --Rot(layer0)--> (f0, f1)
DEVINL void wf(const float* cst, float xw, int w, f32x2& f0, f32x2& f1) {
    float h = 0.5f * xw;
    float s = __sinf(h), c = __cosf(h);
    float m0 = cst[w * 4 + 0], m1 = cst[w * 4 + 1], m2 = cst[w * 4 + 2], m3 = cst[w * 4 + 3];
    f0.x =  m0 * c + m2 * s;
    f0.y =  m1 * c + m3 * s;
    f1.x = -m2 * c + m0 * s;
    f1.y =  m3 * c - m1 * s;
}

// Layer-1 RY gate as fast-Givens on packed {re,im}: a' = a +- t*b.
template<int W>
DEVINL void apply_gate(f32x2 (&a2)[32], const float* cst, int l5) {
    constexpr GC gc = CC.g[10 + W];
    float tt = csw(cst[40 + W], sgnw(l5, gc.rowL));
    f32x2 tp; tp.x = tt;  tp.y = tt;
    f32x2 tn; tn.x = -tt; tn.y = -tt;
    if constexpr (gc.laneXor == 0) {
        #pragma unroll
        for (int r = 0; r < 32; ++r) {
            const int r2 = r ^ gc.regXor;
            if (r < r2) {
                const bool sR  = __builtin_popcount(unsigned(gc.rowR & r )) & 1;
                const bool sR2 = __builtin_popcount(unsigned(gc.rowR & r2)) & 1;
                f32x2 ca = a2[r], cb = a2[r2];
                f32x2 na = ca + (sR  ? tp : tn) * cb;   // -> v_pk_fma, SSA
                f32x2 nb = cb + (sR2 ? tp : tn) * ca;
                a2[r] = na; a2[r2] = nb;
            }
        }
    } else if constexpr (gc.regXor == 0) {
        #pragma unroll
        for (int r = 0; r < 32; ++r) {
            f32x2 b;
            b.x = fetch<gc.laneXor>(a2[r].x);
            b.y = fetch<gc.laneXor>(a2[r].y);
            const bool sR = __builtin_popcount(unsigned(gc.rowR & r)) & 1;
            pk_fma_acc(a2[r], sR ? tp : tn, b);
        }
    } else {
        #pragma unroll
        for (int r = 0; r < 32; ++r) {
            const int r2 = r ^ gc.regXor;
            if (r < r2) {
                f32x2 blo, bhi;
                blo.x = fetch<gc.laneXor>(a2[r2].x);
                blo.y = fetch<gc.laneXor>(a2[r2].y);
                bhi.x = fetch<gc.laneXor>(a2[r].x);
                bhi.y = fetch<gc.laneXor>(a2[r].y);
                const bool sR  = __builtin_popcount(unsigned(gc.rowR & r )) & 1;
                const bool sR2 = __builtin_popcount(unsigned(gc.rowR & r2)) & 1;
                pk_fma_acc(a2[r],  sR  ? tp : tn, blo);
                pk_fma_acc(a2[r2], sR2 ? tp : tn, bhi);
            }
        }
    }
}

__global__ __launch_bounds__(256) void qsim(const float* __restrict__ x,
                                            float* __restrict__ out, int B) {
    const float* cst = g_cst;
    int lane = threadIdx.x & 63;
    int l5 = lane & 31;                        // 5-bit lane within the sample
    int b = blockIdx.x * 8 + (threadIdx.x >> 5);   // 2 samples/wave, 8/block
    if (b >= B) return;

    // ---- vectorized x load: 5x dwordx2 (b*40 bytes ≡ 0 mod 8)
    const f32x2* xp = reinterpret_cast<const f32x2*>(x + b * 10);
    f32x2 xv0 = xp[0], xv1 = xp[1], xv2 = xp[2], xv3 = xp[3], xv4 = xp[4];
    float xw[10] = { xv0.x, xv0.y, xv1.x, xv1.y, xv2.x,
                     xv2.y, xv3.x, xv3.y, xv4.x, xv4.y };

    // ---- reg-wire tables: bit0=w9, bit1=w8, bit2=w7, bit3=w6, bit4=w5
    f32x2 t01[4], t23[4], f5t[2];
    {
        f32x2 a0, a1, b0, b1;
        wf(cst, xw[9], 9, a0, a1);
        wf(cst, xw[8], 8, b0, b1);
        t01[0] = cmul(a0, b0); t01[1] = cmul(a1, b0);
        t01[2] = cmul(a0, b1); t01[3] = cmul(a1, b1);
        wf(cst, xw[7], 7, a0, a1);
        wf(cst, xw[6], 6, b0, b1);
        t23[0] = cmul(a0, b0); t23[1] = cmul(a1, b0);
        t23[2] = cmul(a0, b1); t23[3] = cmul(a1, b1);
        wf(cst, xw[5], 5, f5t[0], f5t[1]);
    }

    // ---- lane factor: selected wire factors (tree) * E_A(w1..w4) * cos-prod
    f32x2 lf;
    {
        f32x2 p0, p1, p2, p3, p4;
        {
            f32x2 f0, f1;
            wf(cst, xw[4], 4, f0, f1);
            int bit = __popc(unsigned(l5 & CC.lsel[0])) & 1;
            p0.x = bit ? f1.x : f0.x;  p0.y = bit ? f1.y : f0.y;
            wf(cst, xw[3], 3, f0, f1);
            bit = __popc(unsigned(l5 & CC.lsel[1])) & 1;
            p1.x = bit ? f1.x : f0.x;  p1.y = bit ? f1.y : f0.y;
            wf(cst, xw[2], 2, f0, f1);
            bit = __popc(unsigned(l5 & CC.lsel[2])) & 1;
            p2.x = bit ? f1.x : f0.x;  p2.y = bit ? f1.y : f0.y;
            wf(cst, xw[1], 1, f0, f1);
            bit = __popc(unsigned(l5 & CC.lsel[3])) & 1;
            p3.x = bit ? f1.x : f0.x;  p3.y = bit ? f1.y : f0.y;
            wf(cst, xw[0], 0, f0, f1);
            bit = __popc(unsigned(l5 & CC.lsel[4])) & 1;
            p4.x = bit ? f1.x : f0.x;  p4.y = bit ? f1.y : f0.y;
        }
        f32x2 pl = cmul(cmul(cmul(p0, p1), cmul(p2, p3)), p4);
        // cumulative E-product (peak 2 temps, not 20 regs)
        f32x2 ea = mkE(cst, 1, l5);
        ea = cmul(ea, mkE(cst, 2, l5));
        ea = cmul(ea, mkE(cst, 3, l5));
        ea = cmul(ea, mkE(cst, 4, l5));
        float sc = cst[70];
        ea.x *= sc; ea.y *= sc;
        lf = cmul(pl, ea);
    }

    // ---- fold w5 phase into f5 (bit4); V (w6,w7) and H (w8,w9,w0) products
    f32x2 f5p[2], V00, V01, H0, H1;
    {
        f32x2 E5 = mkE(cst, 5, l5);
        f5p[0] = cmul(f5t[0], E5);
        E5.y = -E5.y;
        f5p[1] = cmul(f5t[1], E5);
        f32x2 E6 = mkE(cst, 6, l5), E7 = mkE(cst, 7, l5);
        V00 = cmul(E6, E7);
        E7.y = -E7.y;
        V01 = cmul(E6, E7);
        f32x2 EB = cmul(mkE(cst, 9, l5), mkE(cst, 0, l5));
        f32x2 E8 = mkE(cst, 8, l5);
        H0 = cmul(E8, EB);
        EB.y = -EB.y;
        H1 = cmul(E8, EB);
    }

    // ---- g4H[v][conj]: lf * t01[v] * (H(v&1) or conj)
    f32x2 g4H[4][2];
    #pragma unroll
    for (int v = 0; v < 4; ++v) {
        f32x2 g = cmul(lf, t01[v]);
        f32x2 H = (v & 1) ? H1 : H0;
        g4H[v][0] = cmul(g, H);
        f32x2 Hc; Hc.x = H.x; Hc.y = -H.y;
        g4H[v][1] = cmul(g, Hc);
    }

    // ---- amps, j-major (tf folded into the loop; no tf[8] array)
    f32x2 a2[32];
    #pragma unroll
    for (int j = 0; j < 8; ++j) {
        f32x2 tA = cmul(t23[j & 3], f5p[j >> 2]);
        const int s6 = ((j >> 2) ^ (j >> 1)) & 1;
        const int s7 = s6 ^ (j & 1);
        f32x2 V;
        V.x = s6 ? (s7 ? V00.x : V01.x) : (s7 ? V01.x : V00.x);
        V.y = s6 ? -(s7 ? V00.y : V01.y) : (s7 ? V01.y : V00.y);
        f32x2 tfj = cmul(tA, V);
        const int pj = __builtin_popcount(unsigned(j)) & 1;
        #pragma unroll
        for (int v = 0; v < 4; ++v) {
            const int sel = ((v >> 1) ^ pj) & 1;
            a2[(j << 2) | v] = cmul(g4H[v][sel], tfj);
        }
    }

    // ---- layer-1 RY gates (commuting); swizzle gates spread apart
    apply_gate<4>(a2, cst, l5);   // swz16 (reg^16)
    apply_gate<5>(a2, cst, l5);   // local reg^24
    apply_gate<3>(a2, cst, l5);   // DPP xor8 (row_ror:8)
    apply_gate<6>(a2, cst, l5);   // local reg^12
    apply_gate<1>(a2, cst, l5);   // swz12
    apply_gate<7>(a2, cst, l5);   // local reg^6
    apply_gate<2>(a2, cst, l5);   // DPP xor2
    apply_gate<8>(a2, cst, l5);   // local reg^3
    apply_gate<0>(a2, cst, l5);   // DPP xor1
    apply_gate<9>(a2, cst, l5);   // DPP xor1 (reg^1)

    // ---- probabilities + reg-WHT stages 1,2,4,8 (stage 16 pruned into e[q])
    float wv[32];
    #pragma unroll
    for (int r = 0; r < 32; ++r) wv[r] = a2[r].x * a2[r].x + a2[r].y * a2[r].y;
    #pragma unroll
    for (int bS = 1; bS < 16; bS <<= 1) {
        #pragma unroll
        for (int r = 0; r < 32; ++r) {
            if (!(r & bS)) {
                float xvv = wv[r], yv = wv[r | bS];
                wv[r]      = xvv + yv;
                wv[r | bS] = xvv - yv;
            }
        }
    }

    float e[10];
    #pragma unroll
    for (int q = 0; q < 10; ++q) {
        const int R = CC.sgnR[q];
        float num = (R & 16) ? (wv[R ^ 16] - wv[R]) : (wv[R] + wv[R ^ 16]);
        int slq = __popc(unsigned(l5 & CC.sgnL[q])) & 1;
        e[q] = csw(num, slq << 31);
    }

    // ---- lane reduction within each 32-half: DPP quad-reduce, slot-pack to
    //      3, then xor4 (swz) / xor8 (DPP ror8) / xor16 (swz)
    #pragma unroll
    for (int q = 0; q < 10; ++q) {
        e[q] += fetch<1>(e[q]);
        e[q] += fetch<2>(e[q]);
    }
    int s = l5 & 3;
    bool s1 = (s & 1) != 0, s2 = (s & 2) != 0;
    float v0 = s1 ? e[1] : e[0];
    float u0 = s1 ? e[3] : e[2];
    v0 = s2 ? u0 : v0;
    float v1 = s1 ? e[5] : e[4];
    float u1 = s1 ? e[7] : e[6];
    v1 = s2 ? u1 : v1;
    float v2 = s1 ? e[9] : e[8];

    v0 += fetch<4>(v0);   v1 += fetch<4>(v1);   v2 += fetch<4>(v2);
    v0 += fetch<8>(v0);   v1 += fetch<8>(v1);   v2 += fetch<8>(v2);
    v0 += fetch<16>(v0);  v1 += fetch<16>(v1);  v2 += fetch<16>(v2);

    // lane l5==q holds full sum of e[q] in v_{q>>2} (slot matches l5&3)
    float vo = v0;
    int hi = l5 >> 2;
    vo = (hi == 1) ? v1 : vo;
    vo = (hi == 2) ? v2 : vo;
    if (l5 < 10) out[b * 10 + l5] = vo;
}

extern "C" void kernel_launch(void* const* d_in, const int* in_sizes, int n_in,
                              void* d_out, int out_size, void* d_ws, size_t ws_size,
                              hipStream_t stream) {
    const float* x  = (const float*)d_in[0];
    const float* qw = (const float*)d_in[1];
    float* out = (float*)d_out;
    int B = in_sizes[0] / 10;
    int blocks = (B + 7) / 8;   // 8 samples per 256-thread block (2 per wave)
    hipLaunchKernelGGL(qprep, dim3(1), dim3(64), 0, stream, qw);
    hipLaunchKernelGGL(qsim, dim3(blocks), dim3(256), 0, stream, x, out, B);
}